// Round 2
// baseline (139.635 us; speedup 1.0000x reference)
//
#include <hip/hip_runtime.h>

typedef unsigned short u16;
typedef __attribute__((ext_vector_type(8))) short bf16x8;   // 8 bf16 = 4 VGPRs
typedef __attribute__((ext_vector_type(4))) float f32x4;
typedef __attribute__((ext_vector_type(4))) unsigned int u32x4;

#define MFMA16(a, b, c) __builtin_amdgcn_mfma_f32_16x16x32_bf16((a), (b), (c), 0, 0, 0)

static constexpr int Bn = 8, Tn = 2048, Cn = 1024, Hn = 128;

static __device__ __forceinline__ u16 f2bf(float f) {
  union { float f; unsigned u; } v;
  v.f = f;
  unsigned r = v.u + 0x7fffu + ((v.u >> 16) & 1u);
  return (u16)(r >> 16);
}

// ---------------------------------------------------------------------------
// Kernel 1: transpose + bf16-convert the three weight matrices
// W[C][H] (f32) -> Wt[3][H][C] (bf16), so GEMM B-operand loads are contiguous.
// ---------------------------------------------------------------------------
__global__ __launch_bounds__(256) void wt_kernel(const float* __restrict__ Wk,
                                                 const float* __restrict__ Wq,
                                                 const float* __restrict__ Wv,
                                                 u16* __restrict__ Wt) {
  __shared__ u16 tile[64][65];
  const int c0 = blockIdx.x * 64;   // 0..960
  const int h0 = blockIdx.y * 64;   // 0,64
  const int z = blockIdx.z;         // 0=k,1=q,2=v
  const float* W = (z == 0) ? Wk : (z == 1) ? Wq : Wv;
  u16* dst = Wt + (size_t)z * Hn * Cn;
  const int tx = threadIdx.x & 63;
  const int ty = threadIdx.x >> 6;  // 0..3
#pragma unroll
  for (int i = 0; i < 16; ++i) {
    int r = ty * 16 + i;
    tile[r][tx] = f2bf(W[(size_t)(c0 + r) * Hn + h0 + tx]);
  }
  __syncthreads();
#pragma unroll
  for (int i = 0; i < 16; ++i) {
    int r = ty * 16 + i;
    dst[(size_t)(h0 + r) * Cn + c0 + tx] = tile[tx][r];
  }
}

// ---------------------------------------------------------------------------
// Kernel 2: QKV projection.  C[16384][128] = X[16384][1024] * W[1024][128].
// X is f32 (converted to bf16 during staging); Wt is bf16.
// Writes K,Q as [B*T][H] bf16 (Q pre-scaled by 1/sqrt(H)); V transposed
// as Vt[B][H][T] bf16 for the attention PV step.
// ---------------------------------------------------------------------------
__global__ __launch_bounds__(256) void proj_kernel(const float* __restrict__ X,
                                                   const u16* __restrict__ Wt,
                                                   u16* __restrict__ Kb,
                                                   u16* __restrict__ Qb,
                                                   u16* __restrict__ Vt) {
  __shared__ u16 As[128][72];   // x tile (bf16), rows=m, cols=k
  __shared__ u16 Bs[128][72];   // Wt tile, rows=h, cols=k

  const int p = blockIdx.x % 3;          // 0=k,1=q,2=v
  const int m0 = (blockIdx.x / 3) * 128;
  const int tid = threadIdx.x;
  const int lane = tid & 63;
  const int wid = tid >> 6;
  const int wr = (wid >> 1) * 64;        // wave row offset within tile
  const int wc = (wid & 1) * 64;         // wave col offset
  const int l15 = lane & 15, lg = lane >> 4;

  const u16* Wp = Wt + (size_t)p * Hn * Cn;

  f32x4 acc[4][4] = {};

  const int srow = tid >> 3;        // 0..31
  const int scol = (tid & 7) * 8;   // 0..56

  for (int kt = 0; kt < Cn; kt += 64) {
    union { u16 h[8]; u32x4 v; } a_cvt[4];
    u32x4 b_reg[4];
#pragma unroll
    for (int it = 0; it < 4; ++it) {
      int r = srow + it * 32;
      const float* xp = &X[(size_t)(m0 + r) * Cn + kt + scol];
      f32x4 x0 = *reinterpret_cast<const f32x4*>(xp);
      f32x4 x1 = *reinterpret_cast<const f32x4*>(xp + 4);
#pragma unroll
      for (int j = 0; j < 4; ++j) {
        a_cvt[it].h[j] = f2bf(x0[j]);
        a_cvt[it].h[4 + j] = f2bf(x1[j]);
      }
      b_reg[it] = *reinterpret_cast<const u32x4*>(&Wp[(size_t)r * Cn + kt + scol]);
    }
    __syncthreads();   // previous tile fully consumed
#pragma unroll
    for (int it = 0; it < 4; ++it) {
      int r = srow + it * 32;
      *reinterpret_cast<u32x4*>(&As[r][scol]) = a_cvt[it].v;
      *reinterpret_cast<u32x4*>(&Bs[r][scol]) = b_reg[it];
    }
    __syncthreads();
#pragma unroll
    for (int kk = 0; kk < 2; ++kk) {
      const int ko = kk * 32 + lg * 8;
      bf16x8 af[4], bfr[4];
#pragma unroll
      for (int m = 0; m < 4; ++m)
        af[m] = *reinterpret_cast<const bf16x8*>(&As[wr + m * 16 + l15][ko]);
#pragma unroll
      for (int n = 0; n < 4; ++n)
        bfr[n] = *reinterpret_cast<const bf16x8*>(&Bs[wc + n * 16 + l15][ko]);
#pragma unroll
      for (int m = 0; m < 4; ++m)
#pragma unroll
        for (int n = 0; n < 4; ++n)
          acc[m][n] = MFMA16(af[m], bfr[n], acc[m][n]);
    }
  }

  const float oscale = (p == 1) ? 0.08838834764831845f : 1.0f;  // 1/sqrt(128) on Q
#pragma unroll
  for (int m = 0; m < 4; ++m) {
#pragma unroll
    for (int n = 0; n < 4; ++n) {
#pragma unroll
      for (int r = 0; r < 4; ++r) {
        const int row = m0 + wr + m * 16 + lg * 4 + r;   // global row in [0,16384)
        const int col = wc + n * 16 + l15;               // h in [0,128)
        const u16 bv = f2bf(acc[m][n][r] * oscale);
        if (p == 0) {
          Kb[(size_t)row * Hn + col] = bv;
        } else if (p == 1) {
          Qb[(size_t)row * Hn + col] = bv;
        } else {
          const int b = row >> 11, t = row & (Tn - 1);
          Vt[((size_t)b * Hn + col) * Tn + t] = bv;
        }
      }
    }
  }
}

// ---------------------------------------------------------------------------
// Kernel 3: causal flash attention.
// Block = one 16-row q-strip of one batch; 4 waves split the key tiles
// (32 keys each) round-robin; block-level combine of the 4 partials.
// ---------------------------------------------------------------------------
__global__ __launch_bounds__(256) void attn_kernel(const u16* __restrict__ Qb,
                                                   const u16* __restrict__ Kb,
                                                   const u16* __restrict__ Vt,
                                                   float* __restrict__ Out) {
  __shared__ float Om[4][16][128];   // per-wave O partials (32 KB)
  __shared__ float Ml[4][16][2];     // per-wave (m, l) per row
  __shared__ u16 Pl[4][16][40];      // wave-private P staging (C-layout -> A-layout)

  const int strip = blockIdx.x;          // 0..1023
  const int batch = strip >> 7;          // 128 strips per batch
  const int q0 = (strip & 127) << 4;
  const int tid = threadIdx.x;
  const int w = tid >> 6;
  const int lane = tid & 63;
  const int l15 = lane & 15, lg = lane >> 4;

  const size_t bt = (size_t)batch * Tn;

  // Q fragments (A operand): row = q0 + l15, k-chunk = kk*32 + lg*8
  bf16x8 qa[4];
#pragma unroll
  for (int kk = 0; kk < 4; ++kk)
    qa[kk] = *reinterpret_cast<const bf16x8*>(&Qb[(bt + q0 + l15) * Hn + kk * 32 + lg * 8]);

  f32x4 o[8] = {};
  float m_r[4] = {-1e30f, -1e30f, -1e30f, -1e30f};
  float l_r[4] = {0.f, 0.f, 0.f, 0.f};

  const int nt = (q0 + 16 + 31) >> 5;   // key tiles covering keys 0..q0+15
  for (int t = w; t < nt; t += 4) {
    const int k0 = t << 5;

    // ---- S = Q K^T (16q x 32k), two 16-col fragments
    f32x4 s[2] = {};
#pragma unroll
    for (int nf = 0; nf < 2; ++nf) {
#pragma unroll
      for (int kk = 0; kk < 4; ++kk) {
        bf16x8 kb = *reinterpret_cast<const bf16x8*>(
            &Kb[(bt + k0 + nf * 16 + l15) * Hn + kk * 32 + lg * 8]);
        s[nf] = MFMA16(qa[kk], kb, s[nf]);
      }
    }

    // ---- causal mask (only boundary tiles)
    if (k0 + 31 > q0) {
#pragma unroll
      for (int nf = 0; nf < 2; ++nf) {
        const int key = k0 + nf * 16 + l15;
#pragma unroll
        for (int r = 0; r < 4; ++r) {
          const int qrow = q0 + lg * 4 + r;
          if (key > qrow) s[nf][r] = -1e30f;
        }
      }
    }

    // ---- online softmax (rows live across 16 lanes of each lane-group)
    float p0[4], p1[4];
#pragma unroll
    for (int r = 0; r < 4; ++r) {
      float mx = fmaxf(s[0][r], s[1][r]);
      mx = fmaxf(mx, __shfl_xor(mx, 1));
      mx = fmaxf(mx, __shfl_xor(mx, 2));
      mx = fmaxf(mx, __shfl_xor(mx, 4));
      mx = fmaxf(mx, __shfl_xor(mx, 8));
      const float mn = fmaxf(m_r[r], mx);
      const float sc = __expf(m_r[r] - mn);   // ==0 on first tile (m=-1e30)
      p0[r] = __expf(s[0][r] - mn);
      p1[r] = __expf(s[1][r] - mn);
      float rs = p0[r] + p1[r];
      rs += __shfl_xor(rs, 1);
      rs += __shfl_xor(rs, 2);
      rs += __shfl_xor(rs, 4);
      rs += __shfl_xor(rs, 8);
      l_r[r] = l_r[r] * sc + rs;
      m_r[r] = mn;
#pragma unroll
      for (int n = 0; n < 8; ++n) o[n][r] *= sc;
    }

    // ---- P (C-layout) -> LDS -> A-layout fragment, wave-private
#pragma unroll
    for (int r = 0; r < 4; ++r) {
      Pl[w][lg * 4 + r][l15] = f2bf(p0[r]);
      Pl[w][lg * 4 + r][16 + l15] = f2bf(p1[r]);
    }
    asm volatile("s_waitcnt lgkmcnt(0)" ::: "memory");
    bf16x8 pa = *reinterpret_cast<const bf16x8*>(&Pl[w][l15][lg * 8]);
    asm volatile("" ::: "memory");   // pin the read before next iter's writes

    // ---- O += P V  (B operand from Vt[B][H][T], contiguous along T)
#pragma unroll
    for (int n = 0; n < 8; ++n) {
      bf16x8 vb = *reinterpret_cast<const bf16x8*>(
          &Vt[((size_t)batch * Hn + n * 16 + l15) * Tn + k0 + lg * 8]);
      o[n] = MFMA16(pa, vb, o[n]);
    }
  }

  // ---- publish per-wave partials
#pragma unroll
  for (int n = 0; n < 8; ++n)
#pragma unroll
    for (int r = 0; r < 4; ++r)
      Om[w][lg * 4 + r][n * 16 + l15] = o[n][r];
  if (l15 == 0) {
#pragma unroll
    for (int r = 0; r < 4; ++r) {
      Ml[w][lg * 4 + r][0] = m_r[r];
      Ml[w][lg * 4 + r][1] = l_r[r];
    }
  }
  __syncthreads();

  // ---- combine 4 partials; 256 threads cover 16 rows x 128 h (8 h each)
  {
    const int row = tid >> 4;
    const int h0 = (tid & 15) * 8;
    float mw[4], lw[4];
    float M = -1e30f;
#pragma unroll
    for (int i = 0; i < 4; ++i) {
      mw[i] = Ml[i][row][0];
      lw[i] = Ml[i][row][1];
      M = fmaxf(M, mw[i]);
    }
    float e[4], L = 0.f;
#pragma unroll
    for (int i = 0; i < 4; ++i) {
      e[i] = __expf(mw[i] - M);
      L += lw[i] * e[i];
    }
    const float inv = 1.0f / L;
    float outv[8];
#pragma unroll
    for (int j = 0; j < 8; ++j) {
      float a = 0.f;
#pragma unroll
      for (int i = 0; i < 4; ++i) a += e[i] * Om[i][row][h0 + j];
      outv[j] = a * inv;
    }
    float* op = &Out[(bt + q0 + row) * Hn + h0];
    *reinterpret_cast<f32x4*>(op) = *reinterpret_cast<const f32x4*>(&outv[0]);
    *reinterpret_cast<f32x4*>(op + 4) = *reinterpret_cast<const f32x4*>(&outv[4]);
  }
}

// ---------------------------------------------------------------------------
extern "C" void kernel_launch(void* const* d_in, const int* in_sizes, int n_in,
                              void* d_out, int out_size, void* d_ws, size_t ws_size,
                              hipStream_t stream) {
  const float* X = (const float*)d_in[0];
  const float* Wk = (const float*)d_in[1];
  const float* Wq = (const float*)d_in[2];
  const float* Wv = (const float*)d_in[3];

  // workspace layout (bf16):
  //   Wt : 3*128*1024*2          = 786432 B
  //   K  : 16384*128*2           = 4 MiB
  //   Q  : 4 MiB
  //   Vt : [8][128][2048]*2      = 4 MiB
  char* ws = (char*)d_ws;
  u16* Wt = (u16*)(ws);
  u16* Kb = (u16*)(ws + 786432);
  u16* Qb = (u16*)(ws + 786432 + 4194304);
  u16* Vt = (u16*)(ws + 786432 + 2 * 4194304);
  float* Out = (float*)d_out;

  wt_kernel<<<dim3(16, 2, 3), 256, 0, stream>>>(Wk, Wq, Wv, Wt);
  proj_kernel<<<dim3(128 * 3), 256, 0, stream>>>(X, Wt, Kb, Qb, Vt);
  attn_kernel<<<dim3(Bn * Tn / 16), 256, 0, stream>>>(Qb, Kb, Vt, Out);
}

// Round 3
// 126.820 us; speedup vs baseline: 1.1010x; 1.1010x over previous
//
#include <hip/hip_runtime.h>

typedef unsigned short u16;
typedef __attribute__((ext_vector_type(8))) short bf16x8;   // 8 bf16 = 4 VGPRs
typedef __attribute__((ext_vector_type(4))) float f32x4;
typedef __attribute__((ext_vector_type(4))) unsigned int u32x4;

#define MFMA16(a, b, c) __builtin_amdgcn_mfma_f32_16x16x32_bf16((a), (b), (c), 0, 0, 0)

static constexpr int Bn = 8, Tn = 2048, Cn = 1024, Hn = 128;

static __device__ __forceinline__ u16 f2bf(float f) {
  union { float f; unsigned u; } v;
  v.f = f;
  unsigned r = v.u + 0x7fffu + ((v.u >> 16) & 1u);
  return (u16)(r >> 16);
}

static __device__ __forceinline__ float bf2f(u16 h) {
  union { unsigned u; float f; } v;
  v.u = ((unsigned)h) << 16;
  return v.f;
}

// ---------------------------------------------------------------------------
// Kernel 1: transpose + bf16-convert the three weight matrices
// W[C][H] (f32) -> Wt[3][H][C] (bf16), so GEMM B-operand loads are contiguous.
// ---------------------------------------------------------------------------
__global__ __launch_bounds__(256) void wt_kernel(const float* __restrict__ Wk,
                                                 const float* __restrict__ Wq,
                                                 const float* __restrict__ Wv,
                                                 u16* __restrict__ Wt) {
  __shared__ u16 tile[64][65];
  const int c0 = blockIdx.x * 64;   // 0..960
  const int h0 = blockIdx.y * 64;   // 0,64
  const int z = blockIdx.z;         // 0=k,1=q,2=v
  const float* W = (z == 0) ? Wk : (z == 1) ? Wq : Wv;
  u16* dst = Wt + (size_t)z * Hn * Cn;
  const int tx = threadIdx.x & 63;
  const int ty = threadIdx.x >> 6;  // 0..3
#pragma unroll
  for (int i = 0; i < 16; ++i) {
    int r = ty * 16 + i;
    tile[r][tx] = f2bf(W[(size_t)(c0 + r) * Hn + h0 + tx]);
  }
  __syncthreads();
#pragma unroll
  for (int i = 0; i < 16; ++i) {
    int r = ty * 16 + i;
    dst[(size_t)(h0 + r) * Cn + c0 + tx] = tile[tx][r];
  }
}

// ---------------------------------------------------------------------------
// Kernel 2: QKV projection.  C[16384][128] = X[16384][1024] * W[1024][128].
// X is f32 (converted to bf16 during staging); Wt is bf16.
// Writes K,Q as [B*T][H] bf16 (Q pre-scaled by 1/sqrt(H)); V transposed
// as Vt[B][H][T] bf16 for the attention PV step.
// ---------------------------------------------------------------------------
__global__ __launch_bounds__(256) void proj_kernel(const float* __restrict__ X,
                                                   const u16* __restrict__ Wt,
                                                   u16* __restrict__ Kb,
                                                   u16* __restrict__ Qb,
                                                   u16* __restrict__ Vt) {
  __shared__ u16 As[128][72];   // x tile (bf16), rows=m, cols=k
  __shared__ u16 Bs[128][72];   // Wt tile, rows=h, cols=k

  const int p = blockIdx.x % 3;          // 0=k,1=q,2=v
  const int m0 = (blockIdx.x / 3) * 128;
  const int tid = threadIdx.x;
  const int lane = tid & 63;
  const int wid = tid >> 6;
  const int wr = (wid >> 1) * 64;        // wave row offset within tile
  const int wc = (wid & 1) * 64;         // wave col offset
  const int l15 = lane & 15, lg = lane >> 4;

  const u16* Wp = Wt + (size_t)p * Hn * Cn;

  f32x4 acc[4][4] = {};

  const int srow = tid >> 3;        // 0..31
  const int scol = (tid & 7) * 8;   // 0..56

  for (int kt = 0; kt < Cn; kt += 64) {
    union { u16 h[8]; u32x4 v; } a_cvt[4];
    u32x4 b_reg[4];
#pragma unroll
    for (int it = 0; it < 4; ++it) {
      int r = srow + it * 32;
      const float* xp = &X[(size_t)(m0 + r) * Cn + kt + scol];
      f32x4 x0 = *reinterpret_cast<const f32x4*>(xp);
      f32x4 x1 = *reinterpret_cast<const f32x4*>(xp + 4);
#pragma unroll
      for (int j = 0; j < 4; ++j) {
        a_cvt[it].h[j] = f2bf(x0[j]);
        a_cvt[it].h[4 + j] = f2bf(x1[j]);
      }
      b_reg[it] = *reinterpret_cast<const u32x4*>(&Wp[(size_t)r * Cn + kt + scol]);
    }
    __syncthreads();   // previous tile fully consumed
#pragma unroll
    for (int it = 0; it < 4; ++it) {
      int r = srow + it * 32;
      *reinterpret_cast<u32x4*>(&As[r][scol]) = a_cvt[it].v;
      *reinterpret_cast<u32x4*>(&Bs[r][scol]) = b_reg[it];
    }
    __syncthreads();
#pragma unroll
    for (int kk = 0; kk < 2; ++kk) {
      const int ko = kk * 32 + lg * 8;
      bf16x8 af[4], bfr[4];
#pragma unroll
      for (int m = 0; m < 4; ++m)
        af[m] = *reinterpret_cast<const bf16x8*>(&As[wr + m * 16 + l15][ko]);
#pragma unroll
      for (int n = 0; n < 4; ++n)
        bfr[n] = *reinterpret_cast<const bf16x8*>(&Bs[wc + n * 16 + l15][ko]);
#pragma unroll
      for (int m = 0; m < 4; ++m)
#pragma unroll
        for (int n = 0; n < 4; ++n)
          acc[m][n] = MFMA16(af[m], bfr[n], acc[m][n]);
    }
  }

  const float oscale = (p == 1) ? 0.08838834764831845f : 1.0f;  // 1/sqrt(128) on Q
#pragma unroll
  for (int m = 0; m < 4; ++m) {
#pragma unroll
    for (int n = 0; n < 4; ++n) {
#pragma unroll
      for (int r = 0; r < 4; ++r) {
        const int row = m0 + wr + m * 16 + lg * 4 + r;   // global row in [0,16384)
        const int col = wc + n * 16 + l15;               // h in [0,128)
        const u16 bv = f2bf(acc[m][n][r] * oscale);
        if (p == 0) {
          Kb[(size_t)row * Hn + col] = bv;
        } else if (p == 1) {
          Qb[(size_t)row * Hn + col] = bv;
        } else {
          const int b = row >> 11, t = row & (Tn - 1);
          Vt[((size_t)b * Hn + col) * Tn + t] = bv;
        }
      }
    }
  }
}

// ---------------------------------------------------------------------------
// Kernel 3: causal flash attention, v2.
// blockIdx = srank*8 + batch; strip s = 127 - srank (heavy strips first,
// batches pinned to XCDs). Block = one 16-row q-strip; 4 waves split 64-key
// tiles round-robin; bf16 partial combine at the end.
// ---------------------------------------------------------------------------
__global__ __launch_bounds__(256) void attn_kernel(const u16* __restrict__ Qb,
                                                   const u16* __restrict__ Kb,
                                                   const u16* __restrict__ Vt,
                                                   float* __restrict__ Out) {
  __shared__ u16 Om[4][16][128];     // per-wave O partials, bf16 (16 KB)
  __shared__ float Ml[4][16][2];     // per-wave (m, l) per row (512 B)
  __shared__ u16 Pl[4][16][88];      // P staging, padded rows (11.3 KB)

  const int batch = blockIdx.x & 7;
  const int srank = blockIdx.x >> 3;       // 0..127, heavy first
  const int q0 = (127 - srank) << 4;
  const int tid = threadIdx.x;
  const int w = tid >> 6;
  const int lane = tid & 63;
  const int l15 = lane & 15, lg = lane >> 4;

  const size_t bt = (size_t)batch * Tn;

  // Q fragments (A operand): row = q0 + l15, k-chunk = kk*32 + lg*8
  bf16x8 qa[4];
#pragma unroll
  for (int kk = 0; kk < 4; ++kk)
    qa[kk] = *reinterpret_cast<const bf16x8*>(&Qb[(bt + q0 + l15) * Hn + kk * 32 + lg * 8]);

  f32x4 o[8] = {};
  float m_r[4] = {-1e30f, -1e30f, -1e30f, -1e30f};
  float l_r[4] = {0.f, 0.f, 0.f, 0.f};

  const int nt = (q0 + 16 + 63) >> 6;   // 64-key tiles covering keys 0..q0+15
  for (int t = w; t < nt; t += 4) {
    const int k0 = t << 6;

    // ---- S = Q K^T (16q x 64k), four 16-col fragments
    f32x4 s[4] = {};
#pragma unroll
    for (int nf = 0; nf < 4; ++nf) {
#pragma unroll
      for (int kk = 0; kk < 4; ++kk) {
        bf16x8 kb = *reinterpret_cast<const bf16x8*>(
            &Kb[(bt + k0 + nf * 16 + l15) * Hn + kk * 32 + lg * 8]);
        s[nf] = MFMA16(qa[kk], kb, s[nf]);
      }
    }

    // ---- causal mask (only boundary tiles)
    if (k0 + 63 > q0) {
#pragma unroll
      for (int nf = 0; nf < 4; ++nf) {
        const int key = k0 + nf * 16 + l15;
#pragma unroll
        for (int r = 0; r < 4; ++r) {
          const int qrow = q0 + lg * 4 + r;
          if (key > qrow) s[nf][r] = -1e30f;
        }
      }
    }

    // ---- online softmax (row lives across 16 lanes of each lane-group)
#pragma unroll
    for (int r = 0; r < 4; ++r) {
      float mx = fmaxf(fmaxf(s[0][r], s[1][r]), fmaxf(s[2][r], s[3][r]));
      mx = fmaxf(mx, __shfl_xor(mx, 1));
      mx = fmaxf(mx, __shfl_xor(mx, 2));
      mx = fmaxf(mx, __shfl_xor(mx, 4));
      mx = fmaxf(mx, __shfl_xor(mx, 8));
      const float mn = fmaxf(m_r[r], mx);
      const float sc = __expf(m_r[r] - mn);   // ==0 on first tile (m=-1e30)
#pragma unroll
      for (int nf = 0; nf < 4; ++nf) s[nf][r] = __expf(s[nf][r] - mn);
      float rs = (s[0][r] + s[1][r]) + (s[2][r] + s[3][r]);
      rs += __shfl_xor(rs, 1);
      rs += __shfl_xor(rs, 2);
      rs += __shfl_xor(rs, 4);
      rs += __shfl_xor(rs, 8);
      l_r[r] = l_r[r] * sc + rs;
      m_r[r] = mn;
#pragma unroll
      for (int n = 0; n < 8; ++n) o[n][r] *= sc;
    }

    // ---- P (C-layout) -> LDS -> A-layout fragments, wave-private
#pragma unroll
    for (int nf = 0; nf < 4; ++nf)
#pragma unroll
      for (int r = 0; r < 4; ++r)
        Pl[w][lg * 4 + r][nf * 16 + l15] = f2bf(s[nf][r]);
    asm volatile("s_waitcnt lgkmcnt(0)" ::: "memory");
    bf16x8 pa0 = *reinterpret_cast<const bf16x8*>(&Pl[w][l15][lg * 8]);
    bf16x8 pa1 = *reinterpret_cast<const bf16x8*>(&Pl[w][l15][32 + lg * 8]);
    asm volatile("" ::: "memory");   // pin reads before next iter's writes

    // ---- O += P V  (B operand from Vt[B][H][T], contiguous along T)
#pragma unroll
    for (int n = 0; n < 8; ++n) {
      const u16* vp = &Vt[((size_t)batch * Hn + n * 16 + l15) * Tn + k0 + lg * 8];
      bf16x8 vb0 = *reinterpret_cast<const bf16x8*>(vp);
      bf16x8 vb1 = *reinterpret_cast<const bf16x8*>(vp + 32);
      o[n] = MFMA16(pa0, vb0, o[n]);
      o[n] = MFMA16(pa1, vb1, o[n]);
    }
  }

  // ---- publish per-wave partials (O in bf16)
#pragma unroll
  for (int n = 0; n < 8; ++n)
#pragma unroll
    for (int r = 0; r < 4; ++r)
      Om[w][lg * 4 + r][n * 16 + l15] = f2bf(o[n][r]);
  if (l15 == 0) {
#pragma unroll
    for (int r = 0; r < 4; ++r) {
      Ml[w][lg * 4 + r][0] = m_r[r];
      Ml[w][lg * 4 + r][1] = l_r[r];
    }
  }
  __syncthreads();

  // ---- combine 4 partials; 256 threads cover 16 rows x 128 h (8 h each)
  {
    const int row = tid >> 4;
    const int h0 = (tid & 15) * 8;
    float mw[4], lw[4];
    float M = -1e30f;
#pragma unroll
    for (int i = 0; i < 4; ++i) {
      mw[i] = Ml[i][row][0];
      lw[i] = Ml[i][row][1];
      M = fmaxf(M, mw[i]);
    }
    float e[4], L = 0.f;
#pragma unroll
    for (int i = 0; i < 4; ++i) {
      e[i] = __expf(mw[i] - M);
      L += lw[i] * e[i];
    }
    const float inv = 1.0f / L;
    float outv[8];
#pragma unroll
    for (int j = 0; j < 8; ++j) {
      float a = 0.f;
#pragma unroll
      for (int i = 0; i < 4; ++i) a += e[i] * bf2f(Om[i][row][h0 + j]);
      outv[j] = a * inv;
    }
    float* op = &Out[(bt + q0 + row) * Hn + h0];
    *reinterpret_cast<f32x4*>(op) = *reinterpret_cast<const f32x4*>(&outv[0]);
    *reinterpret_cast<f32x4*>(op + 4) = *reinterpret_cast<const f32x4*>(&outv[4]);
  }
}

// ---------------------------------------------------------------------------
extern "C" void kernel_launch(void* const* d_in, const int* in_sizes, int n_in,
                              void* d_out, int out_size, void* d_ws, size_t ws_size,
                              hipStream_t stream) {
  const float* X = (const float*)d_in[0];
  const float* Wk = (const float*)d_in[1];
  const float* Wq = (const float*)d_in[2];
  const float* Wv = (const float*)d_in[3];

  // workspace layout (bf16):
  //   Wt : 3*128*1024*2          = 786432 B
  //   K  : 16384*128*2           = 4 MiB
  //   Q  : 4 MiB
  //   Vt : [8][128][2048]*2      = 4 MiB
  char* ws = (char*)d_ws;
  u16* Wt = (u16*)(ws);
  u16* Kb = (u16*)(ws + 786432);
  u16* Qb = (u16*)(ws + 786432 + 4194304);
  u16* Vt = (u16*)(ws + 786432 + 2 * 4194304);
  float* Out = (float*)d_out;

  wt_kernel<<<dim3(16, 2, 3), 256, 0, stream>>>(Wk, Wq, Wv, Wt);
  proj_kernel<<<dim3(128 * 3), 256, 0, stream>>>(X, Wt, Kb, Qb, Vt);
  attn_kernel<<<dim3(Bn * Tn / 16), 256, 0, stream>>>(Qb, Kb, Vt, Out);
}